// Round 6
// baseline (133.983 us; speedup 1.0000x reference)
//
#include <hip/hip_runtime.h>
#include <cmath>

#define IMG      512
#define OUT      502            // 512 - 11 + 1
#define TW       64             // output tile width
#define TH       32             // output tile height
#define IW       74             // input tile width  (TW + 10)
#define P2       78             // LDS row pitch in float2 units
#define NTHREADS 256
#define TILES_X  8
#define TILES_Y  16
#define NIMG     32
#define NBLOCKS  (TILES_X * TILES_Y * NIMG)

struct GaussW { float w[11]; };

// ---------------------------------------------------------------------------
// Fused SSIM tile kernel, time-multiplexed single LDS plane (20 KB) for
// ~7 blocks/CU occupancy (R4/R5 had 40 KB -> 4 blocks/CU, 30% idle issue).
//  A: vblur {X,Y} -> LDS -> hblur -> mu1,mu2 in regs
//  B: reload x,y (L1-hot), vblur {XX+YY, XY} -> same LDS -> hblur -> SSIM
// Edge tiles shifted inward; ownership predicate prevents double counting.
// ---------------------------------------------------------------------------
__global__ __launch_bounds__(NTHREADS, 6)
void ssim_tile_kernel(const float* __restrict__ ypred,
                      const float* __restrict__ ytrue,
                      float* __restrict__ partials,
                      GaussW gw)
{
    __shared__ __align__(16) float2 sP[TH * P2];    // 19968 B, reused A then B
    __shared__ float wsum[4];

    const int t     = threadIdx.x;
    const int tileX = blockIdx.x, tileY = blockIdx.y, img = blockIdx.z;
    // shift last tiles inward so ALL loads are in-bounds (no clamps)
    const int ox0 = (tileX == TILES_X - 1) ? (OUT - TW) : tileX * TW;  // <=438
    const int oy0 = (tileY == TILES_Y - 1) ? (OUT - TH) : tileY * TH;  // <=470

    const size_t imgoff = (size_t)img * (IMG * IMG);
    const float* __restrict__ Xp = ytrue + imgoff;   // X = y_true
    const float* __restrict__ Yp = ypred + imgoff;   // Y = y_pred

    // phase-1 work item: 74 cols x 3 row-groups (11,11,10 outputs) = 222
    const bool p1   = (t < IW * 3);
    const int  c    = t % IW;
    const int  g    = t / IW;
    const int  r0   = g * 11;
    const unsigned off0 = (unsigned)((oy0 + r0) * IMG + (ox0 + c));
    const int  o0   = r0 * P2 + c;

    // phase-2 work item: (row = t&31, seg = t>>5) -> 8 output cols
    const int row    = t & 31;
    const int seg    = t >> 5;
    const int basef2 = row * P2 + seg * 8;

    // ================= sub-phase A : maps {X, Y} =================
    if (p1) {
        float aX[11], aY[11];
        #pragma unroll
        for (int j = 0; j < 11; ++j) { aX[j] = 0.f; aY[j] = 0.f; }

        #pragma unroll
        for (int k = 0; k < 20; ++k) {
            const float x = Xp[off0 + k * IMG];
            const float y = Yp[off0 + k * IMG];
            #pragma unroll
            for (int j = 0; j < 11; ++j) {
                if (k - j >= 0 && k - j <= 10) {            // folds per (k,j)
                    const float w = gw.w[k - j];
                    aX[j] = __builtin_fmaf(w, x, aX[j]);
                    aY[j] = __builtin_fmaf(w, y, aY[j]);
                }
            }
        }
        if (g < 2) {                                        // k=20 -> j=10 only
            const float x = Xp[off0 + 20 * IMG];
            const float y = Yp[off0 + 20 * IMG];
            aX[10] = __builtin_fmaf(gw.w[10], x, aX[10]);
            aY[10] = __builtin_fmaf(gw.w[10], y, aY[10]);
        }

        #pragma unroll
        for (int j = 0; j < 10; ++j) sP[o0 + j * P2] = make_float2(aX[j], aY[j]);
        if (g < 2)                   sP[o0 + 10 * P2] = make_float2(aX[10], aY[10]);
    }
    __syncthreads();

    // horizontal blur of {X,Y} -> mu1, mu2 (kept in registers)
    float mu1[8], mu2[8];
    {
        float wA[18], wB[18];
        const float4* q = reinterpret_cast<const float4*>(&sP[basef2]);
        #pragma unroll
        for (int i = 0; i < 9; ++i) {
            const float4 v = q[i];
            wA[2*i] = v.x;  wB[2*i] = v.y;
            wA[2*i+1] = v.z;  wB[2*i+1] = v.w;
        }
        #pragma unroll
        for (int cc = 0; cc < 8; ++cc) {
            float r1 = 0.f, r2 = 0.f;
            #pragma unroll
            for (int k = 0; k < 11; ++k) {
                const float w = gw.w[k];
                r1 = __builtin_fmaf(w, wA[cc + k], r1);
                r2 = __builtin_fmaf(w, wB[cc + k], r2);
            }
            mu1[cc] = r1; mu2[cc] = r2;
        }
    }
    __syncthreads();                                        // LDS reads done

    // ================= sub-phase B : maps {XX+YY, XY} =================
    if (p1) {
        float aS[11], aP[11];
        #pragma unroll
        for (int j = 0; j < 11; ++j) { aS[j] = 0.f; aP[j] = 0.f; }

        #pragma unroll
        for (int k = 0; k < 20; ++k) {
            const float x = Xp[off0 + k * IMG];             // L1-hot reload
            const float y = Yp[off0 + k * IMG];
            const float s = __builtin_fmaf(y, y, x * x);    // XX + YY
            const float p = x * y;                          // XY
            #pragma unroll
            for (int j = 0; j < 11; ++j) {
                if (k - j >= 0 && k - j <= 10) {
                    const float w = gw.w[k - j];
                    aS[j] = __builtin_fmaf(w, s, aS[j]);
                    aP[j] = __builtin_fmaf(w, p, aP[j]);
                }
            }
        }
        if (g < 2) {
            const float x = Xp[off0 + 20 * IMG];
            const float y = Yp[off0 + 20 * IMG];
            aS[10] = __builtin_fmaf(gw.w[10], __builtin_fmaf(y, y, x * x), aS[10]);
            aP[10] = __builtin_fmaf(gw.w[10], x * y, aP[10]);
        }

        #pragma unroll
        for (int j = 0; j < 10; ++j) sP[o0 + j * P2] = make_float2(aS[j], aP[j]);
        if (g < 2)                   sP[o0 + 10 * P2] = make_float2(aS[10], aP[10]);
    }
    __syncthreads();

    // horizontal blur of {S,P} + SSIM + reduce
    const float C1 = 0.0001f;   // (0.01*1)^2
    const float C2 = 0.0009f;   // (0.03*1)^2

    float wA[18], wB[18];
    {
        const float4* q = reinterpret_cast<const float4*>(&sP[basef2]);
        #pragma unroll
        for (int i = 0; i < 9; ++i) {
            const float4 v = q[i];
            wA[2*i] = v.x;  wB[2*i] = v.y;
            wA[2*i+1] = v.z;  wB[2*i+1] = v.w;
        }
    }

    const int  oy     = oy0 + row;
    const bool rowown = (oy >= tileY * TH);                 // edge-shift ownership
    float lsum = 0.f;

    #pragma unroll
    for (int cc = 0; cc < 8; ++cc) {
        float b3 = 0.f, b4 = 0.f;
        #pragma unroll
        for (int k = 0; k < 11; ++k) {
            const float w = gw.w[k];
            b3 = __builtin_fmaf(w, wA[cc + k], b3);         // blur(XX+YY)
            b4 = __builtin_fmaf(w, wB[cc + k], b4);         // blur(XY)
        }
        const int  ox  = ox0 + seg * 8 + cc;
        const bool own = rowown && (ox >= tileX * TW);
        const float m1 = mu1[cc], m2 = mu2[cc];
        const float Pm = m1 * m2;
        const float Sm = __builtin_fmaf(m1, m1, m2 * m2);
        const float num = __builtin_fmaf(2.f, Pm, C1) * __builtin_fmaf(2.f, b4 - Pm, C2);
        const float den = (Sm + C1) * ((b3 + C2) - Sm);
        const float ssim = num * __builtin_amdgcn_rcpf(den);
        lsum += own ? ssim : 0.f;
    }

    // ---------------- Block reduction ----------------
    #pragma unroll
    for (int off = 32; off > 0; off >>= 1) lsum += __shfl_down(lsum, off, 64);
    if ((t & 63) == 0) wsum[t >> 6] = lsum;
    __syncthreads();
    if (t == 0) {
        const float b = wsum[0] + wsum[1] + wsum[2] + wsum[3];
        partials[((size_t)img * TILES_Y + tileY) * TILES_X + tileX] = b;
    }
}

// ---------------------------------------------------------------------------
// Final reduction: 4096 partials -> 1 - mean
// ---------------------------------------------------------------------------
__global__ void ssim_reduce_kernel(const float* __restrict__ partials,
                                   float* __restrict__ out)
{
    __shared__ double ws[4];
    const int t = threadIdx.x;
    double s = 0.0;
    for (int i = t; i < NBLOCKS; i += 256) s += (double)partials[i];
    #pragma unroll
    for (int off = 32; off > 0; off >>= 1) s += __shfl_down(s, off, 64);
    if ((t & 63) == 0) ws[t >> 6] = s;
    __syncthreads();
    if (t == 0) {
        const double total = ws[0] + ws[1] + ws[2] + ws[3];
        const double mean  = total / ((double)OUT * (double)OUT * (double)NIMG);
        out[0] = (float)(1.0 - mean);
    }
}

extern "C" void kernel_launch(void* const* d_in, const int* in_sizes, int n_in,
                              void* d_out, int out_size, void* d_ws, size_t ws_size,
                              hipStream_t stream)
{
    const float* ypred = (const float*)d_in[0];   // y_pred
    const float* ytrue = (const float*)d_in[1];   // y_true
    float* out      = (float*)d_out;
    float* partials = (float*)d_ws;               // NBLOCKS * 4 B = 16 KB

    // Gaussian weights: float64 math + normalize, then cast — matches reference.
    GaussW gw;
    double g[11], sum = 0.0;
    for (int i = 0; i < 11; ++i) {
        const double c = (double)i - 5.0;
        g[i] = std::exp(-(c * c) / (2.0 * 1.5 * 1.5));
        sum += g[i];
    }
    for (int i = 0; i < 11; ++i) gw.w[i] = (float)(g[i] / sum);

    dim3 grid(TILES_X, TILES_Y, NIMG);
    ssim_tile_kernel<<<grid, NTHREADS, 0, stream>>>(ypred, ytrue, partials, gw);
    ssim_reduce_kernel<<<1, 256, 0, stream>>>(partials, out);
}

// Round 9
// 126.477 us; speedup vs baseline: 1.0594x; 1.0594x over previous
//
#include <hip/hip_runtime.h>
#include <cmath>

#define IMG      512
#define OUT      502            // 512 - 11 + 1
#define TW       64             // output tile width
#define THF      32             // full tile height
#define HH       16             // half height (pipelined unit)
#define IW       74             // input tile width (TW + 10)
#define P2       78             // LDS row pitch in float2 units
#define NTHREADS 256
#define TILES_X  8
#define TILES_Y  16
#define NIMG     32
#define NBLOCKS  (TILES_X * TILES_Y * NIMG)

struct GaussW { float w[11]; };

// ---------------------------------------------------------------------------
// Fused SSIM, pipelined half-tiles. Block = 64x32 outputs as two 16-row
// halves with ping-pong LDS planes (39.9 KB total, 4 blocks/CU):
//   P1(h0) -> bar -> [ issue P1 loads(h1) | P2(h0) compute | P1 acc(h1) ]
//            -> bar -> P2(h1)
// The h1 global loads are in flight UNDER P2(h0)'s ~400 LDS-fed FMAs (T14
// async-stage split) -- R4-R6 showed neither reg-batching (R5 neutral) nor
// raw occupancy (R6 regression: 2x FETCH + spills) fixes the latency stall;
// single-pass traffic + in-thread overlap is the remaining lever.
// Phase 1: two EQUAL 8-row groups (148 thr, group id is data not branch ->
// no divergence). Phase 2: 4 cols x (row=t&15, seg=t>>4), 256 thr/half.
// ---------------------------------------------------------------------------
__global__ __launch_bounds__(NTHREADS, 4)
void ssim_tile_kernel(const float* __restrict__ ypred,
                      const float* __restrict__ ytrue,
                      float* __restrict__ partials,
                      GaussW gw)
{
    __shared__ __align__(16) float2 sXY[2][HH * P2];   // (vblur X, vblur Y)
    __shared__ __align__(16) float2 sSP[2][HH * P2];   // (vblur XX+YY, vblur XY)
    __shared__ float wsum[4];

    const int t     = threadIdx.x;
    const int tileX = blockIdx.x, tileY = blockIdx.y;
    // shift last tiles inward so ALL loads are in-bounds (no clamps)
    const int ox0 = (tileX == TILES_X - 1) ? (OUT - TW)  : tileX * TW;   // <=438
    const int oy0 = (tileY == TILES_Y - 1) ? (OUT - THF) : tileY * THF;  // <=470

    const size_t imgoff = (size_t)blockIdx.z * (IMG * IMG);
    const float* __restrict__ Xp = ytrue + imgoff;   // X = y_true
    const float* __restrict__ Yp = ypred + imgoff;   // Y = y_pred

    // ---- phase-1 item: (col, group) ; 2 equal groups of 8 output rows ----
    const bool p1 = (t < 2 * IW);
    const int  g  = (t >= IW) ? 1 : 0;       // value, not branch: no divergence
    const int  c  = t - g * IW;              // 0..73  (valid when p1)
    const int  r0 = g * 8;
    const unsigned off0 = (unsigned)((oy0 + r0) * IMG + (ox0 + c));
    const int  o0 = r0 * P2 + c;

    // ---- phase-2 item: (row = t&15, seg = t>>4) -> 4 output cols ----
    // bank check: 16 consecutive lanes = rows, row stride 156 dwords = bank
    // +28/row -> 8 distinct start banks, 2 lanes each: 2-way = free (m136).
    const int prow = t & 15;
    const int pseg = t >> 4;
    const int pb   = prow * P2 + pseg * 4;   // f2 index; cols pseg*4..pseg*4+13

    const float C1 = 0.0001f;   // (0.01*1)^2
    const float C2 = 0.0009f;   // (0.03*1)^2

    float xv[18], yv[18];
    float lsum = 0.f;

#define P1LOAD(OFF) do {                                                      \
    _Pragma("unroll")                                                         \
    for (int k = 0; k < 18; ++k) {                                            \
        xv[k] = Xp[(OFF) + k * IMG];                                          \
        yv[k] = Yp[(OFF) + k * IMG];                                          \
    } } while (0)

#define P1ACC(BUF) do {                                                       \
    float aX[8], aY[8], aS[8], aP[8];                                         \
    _Pragma("unroll")                                                         \
    for (int j = 0; j < 8; ++j) { aX[j]=0.f; aY[j]=0.f; aS[j]=0.f; aP[j]=0.f; } \
    _Pragma("unroll")                                                         \
    for (int k = 0; k < 18; ++k) {                                            \
        const float x = xv[k], y = yv[k];                                     \
        const float s = __builtin_fmaf(y, y, x * x);   /* XX + YY */          \
        const float p = x * y;                          /* XY */              \
        _Pragma("unroll")                                                     \
        for (int j = 0; j < 8; ++j) {                                         \
            if (k - j >= 0 && k - j <= 10) {           /* folds per (k,j) */  \
                const float w = gw.w[k - j];                                  \
                aX[j] = __builtin_fmaf(w, x, aX[j]);                          \
                aY[j] = __builtin_fmaf(w, y, aY[j]);                          \
                aS[j] = __builtin_fmaf(w, s, aS[j]);                          \
                aP[j] = __builtin_fmaf(w, p, aP[j]);                          \
            }                                                                 \
        }                                                                     \
    }                                                                         \
    _Pragma("unroll")                                                         \
    for (int j = 0; j < 8; ++j) {                                             \
        sXY[BUF][o0 + j * P2] = make_float2(aX[j], aY[j]);                    \
        sSP[BUF][o0 + j * P2] = make_float2(aS[j], aP[j]);                    \
    } } while (0)

#define P2SSIM(BUF, H) do {                                                   \
    float wA[14], wB[14];                                                     \
    { const float4* q = reinterpret_cast<const float4*>(&sXY[BUF][pb]);       \
      _Pragma("unroll")                                                       \
      for (int i = 0; i < 7; ++i) { const float4 v = q[i];                    \
          wA[2*i] = v.x; wB[2*i] = v.y; wA[2*i+1] = v.z; wB[2*i+1] = v.w; } } \
    float mu1[4], mu2[4];                                                     \
    _Pragma("unroll")                                                         \
    for (int cc = 0; cc < 4; ++cc) {                                          \
        float r1 = 0.f, r2 = 0.f;                                             \
        _Pragma("unroll")                                                     \
        for (int k = 0; k < 11; ++k) {                                        \
            const float w = gw.w[k];                                          \
            r1 = __builtin_fmaf(w, wA[cc + k], r1);                           \
            r2 = __builtin_fmaf(w, wB[cc + k], r2);                           \
        }                                                                     \
        mu1[cc] = r1; mu2[cc] = r2;                                           \
    }                                                                         \
    { const float4* q = reinterpret_cast<const float4*>(&sSP[BUF][pb]);       \
      _Pragma("unroll")                                                       \
      for (int i = 0; i < 7; ++i) { const float4 v = q[i];                    \
          wA[2*i] = v.x; wB[2*i] = v.y; wA[2*i+1] = v.z; wB[2*i+1] = v.w; } } \
    const int  oyq    = oy0 + (H) * HH + prow;                                \
    const bool rowown = (oyq >= tileY * THF);                                 \
    _Pragma("unroll")                                                         \
    for (int cc = 0; cc < 4; ++cc) {                                          \
        float b3 = 0.f, b4 = 0.f;                                             \
        _Pragma("unroll")                                                     \
        for (int k = 0; k < 11; ++k) {                                        \
            const float w = gw.w[k];                                          \
            b3 = __builtin_fmaf(w, wA[cc + k], b3);   /* blur(XX+YY) */       \
            b4 = __builtin_fmaf(w, wB[cc + k], b4);   /* blur(XY)    */       \
        }                                                                     \
        const int  oxq = ox0 + pseg * 4 + cc;                                 \
        const bool own = rowown && (oxq >= tileX * TW);                       \
        const float m1 = mu1[cc], m2 = mu2[cc];                               \
        const float Pm = m1 * m2;                                             \
        const float Sm = __builtin_fmaf(m1, m1, m2 * m2);                     \
        const float num = __builtin_fmaf(2.f, Pm, C1)                         \
                        * __builtin_fmaf(2.f, b4 - Pm, C2);                   \
        const float den = (Sm + C1) * ((b3 + C2) - Sm);                       \
        lsum += own ? num * __builtin_amdgcn_rcpf(den) : 0.f;                 \
    } } while (0)

    // ---------------- pipeline ----------------
    if (p1) { P1LOAD(off0); P1ACC(0); }
    __syncthreads();
    if (p1) { P1LOAD(off0 + HH * IMG); }      // h1 loads in flight under P2(h0)
    P2SSIM(0, 0);
    if (p1) { P1ACC(1); }
    __syncthreads();
    P2SSIM(1, 1);

    // ---------------- block reduction ----------------
    #pragma unroll
    for (int off = 32; off > 0; off >>= 1) lsum += __shfl_down(lsum, off, 64);
    if ((t & 63) == 0) wsum[t >> 6] = lsum;
    __syncthreads();
    if (t == 0) {
        partials[((size_t)blockIdx.z * TILES_Y + tileY) * TILES_X + tileX]
            = wsum[0] + wsum[1] + wsum[2] + wsum[3];
    }
#undef P1LOAD
#undef P1ACC
#undef P2SSIM
}

// ---------------------------------------------------------------------------
// Final reduction: 4096 partials -> 1 - mean
// ---------------------------------------------------------------------------
__global__ void ssim_reduce_kernel(const float* __restrict__ partials,
                                   float* __restrict__ out)
{
    __shared__ double ws[4];
    const int t = threadIdx.x;
    double s = 0.0;
    for (int i = t; i < NBLOCKS; i += 256) s += (double)partials[i];
    #pragma unroll
    for (int off = 32; off > 0; off >>= 1) s += __shfl_down(s, off, 64);
    if ((t & 63) == 0) ws[t >> 6] = s;
    __syncthreads();
    if (t == 0) {
        const double total = ws[0] + ws[1] + ws[2] + ws[3];
        const double mean  = total / ((double)OUT * (double)OUT * (double)NIMG);
        out[0] = (float)(1.0 - mean);
    }
}

extern "C" void kernel_launch(void* const* d_in, const int* in_sizes, int n_in,
                              void* d_out, int out_size, void* d_ws, size_t ws_size,
                              hipStream_t stream)
{
    const float* ypred = (const float*)d_in[0];   // y_pred
    const float* ytrue = (const float*)d_in[1];   // y_true
    float* out      = (float*)d_out;
    float* partials = (float*)d_ws;               // NBLOCKS * 4 B = 16 KB

    // Gaussian weights: float64 math + normalize, then cast — matches reference.
    GaussW gw;
    double g[11], sum = 0.0;
    for (int i = 0; i < 11; ++i) {
        const double c = (double)i - 5.0;
        g[i] = std::exp(-(c * c) / (2.0 * 1.5 * 1.5));
        sum += g[i];
    }
    for (int i = 0; i < 11; ++i) gw.w[i] = (float)(g[i] / sum);

    dim3 grid(TILES_X, TILES_Y, NIMG);
    ssim_tile_kernel<<<grid, NTHREADS, 0, stream>>>(ypred, ytrue, partials, gw);
    ssim_reduce_kernel<<<1, 256, 0, stream>>>(partials, out);
}